// Round 5
// baseline (528.290 us; speedup 1.0000x reference)
//
#include <hip/hip_runtime.h>

#define N_NODES 100000
#define D 64
#define BIN_ROWS 64
#define NBINS 1563          // ceil(100000 / 64)
#define PE 16384            // edges per partition block

typedef unsigned int u32;

__device__ __forceinline__ float bf16_to_f32(unsigned short u) {
    union { u32 i; float f; } c; c.i = ((u32)u) << 16; return c.f;
}
__device__ __forceinline__ unsigned short f32_to_bf16(float f) {
    union { float f; u32 i; } c; c.f = f;
    const u32 u = c.i;
    return (unsigned short)((u + 0x7FFFu + ((u >> 16) & 1u)) >> 16);
}

// ---------------- y = bf16(x @ W^T); block 0 zeroes binCounts ----------------
__global__ __launch_bounds__(256) void xw_kernel(const float* __restrict__ x,
                                                 const float* __restrict__ W,
                                                 unsigned short* __restrict__ y,
                                                 int* __restrict__ binCounts) {
    __shared__ float Ws[D][D + 1];
    __shared__ float xs[32][D];

    const int tid = threadIdx.x;
    if (blockIdx.x == 0) {
        for (int i = tid; i < NBINS; i += 256) binCounts[i] = 0;
    }
    for (int i = tid; i < D * D; i += 256) Ws[i >> 6][i & 63] = W[i];

    const int nodeBase = blockIdx.x * 32;
    for (int i = tid; i < 32 * D; i += 256) {
        const int n = nodeBase + (i >> 6);
        xs[i >> 6][i & 63] = (n < N_NODES) ? x[n * D + (i & 63)] : 0.f;
    }
    __syncthreads();

    const int wave = tid >> 6, j = tid & 63;
    for (int s = 0; s < 8; ++s) {
        const int local = wave * 8 + s;
        const int n = nodeBase + local;
        if (n >= N_NODES) break;
        float acc = 0.f;
#pragma unroll
        for (int k = 0; k < D; ++k) acc += xs[local][k] * Ws[j][k];
        y[n * D + j] = f32_to_bf16(acc);
    }
}

// ---------------- per-block LDS histogram of row>>6 ----------------
__global__ __launch_bounds__(256) void binhist_kernel(const int* __restrict__ erow,
                                                      int* __restrict__ binCounts, int ne) {
    __shared__ int h[NBINS];
    for (int i = threadIdx.x; i < NBINS; i += 256) h[i] = 0;
    __syncthreads();
    const int stride = gridDim.x * 256;
    for (int e = blockIdx.x * 256 + threadIdx.x; e < ne; e += stride)
        atomicAdd(&h[erow[e] >> 6], 1);
    __syncthreads();
    for (int i = threadIdx.x; i < NBINS; i += 256)
        if (h[i]) atomicAdd(&binCounts[i], h[i]);
}

// ---------------- single-block exclusive scan of 1563 bin counts ----------------
__global__ __launch_bounds__(512) void binscan_kernel(const int* __restrict__ binCounts,
                                                      int* __restrict__ binOff,
                                                      int* __restrict__ binCursor) {
    __shared__ int sdat[512];
    const int tid = threadIdx.x;
    int v[4], sum = 0;
#pragma unroll
    for (int k = 0; k < 4; ++k) {
        const int i = tid * 4 + k;
        v[k] = (i < NBINS) ? binCounts[i] : 0;
        sum += v[k];
    }
    sdat[tid] = sum;
    __syncthreads();
    for (int d = 1; d < 512; d <<= 1) {
        const int t = (tid >= d) ? sdat[tid - d] : 0;
        __syncthreads();
        sdat[tid] += t;
        __syncthreads();
    }
    int run = sdat[tid] - sum;   // exclusive prefix of this thread's 4 elems
#pragma unroll
    for (int k = 0; k < 4; ++k) {
        const int i = tid * 4 + k;
        if (i < NBINS) { binOff[i] = run; binCursor[i] = run; }
        run += v[k];
    }
    if (tid == 511) binOff[NBINS] = sdat[511];
}

// ---------------- partition: pack (col,localrow,q9val) into u32, bin-grouped ----------------
__global__ __launch_bounds__(256) void partition_kernel(const int* __restrict__ erow,
                                                        const int* __restrict__ ecol,
                                                        const float* __restrict__ eval_,
                                                        int* __restrict__ binCursor,
                                                        u32* __restrict__ pedge, int ne) {
    __shared__ int h[NBINS];
    __shared__ int lcur[NBINS];
    for (int i = threadIdx.x; i < NBINS; i += 256) h[i] = 0;
    __syncthreads();
    const int base = blockIdx.x * PE;
    const int end  = min(base + PE, ne);
    for (int e = base + threadIdx.x; e < end; e += 256)
        atomicAdd(&h[erow[e] >> 6], 1);
    __syncthreads();
    for (int i = threadIdx.x; i < NBINS; i += 256) {
        const int c = h[i];
        lcur[i] = c ? atomicAdd(&binCursor[i], c) : 0;
    }
    __syncthreads();
    for (int e = base + threadIdx.x; e < end; e += 256) {
        const int r = erow[e];
        const int bin = r >> 6;
        const int pos = atomicAdd(&lcur[bin], 1);
        int q = (int)(eval_[e] * 512.0f + 0.5f);
        q = (q > 511) ? 511 : q;
        pedge[pos] = ((u32)ecol[e] << 15) | ((u32)(r & 63) << 9) | (u32)q;
    }
}

// ---------------- aggregate: one block per 64-row bin, 16KB LDS acc ----------------
__global__ __launch_bounds__(256) void aggregate_kernel(const int* __restrict__ binOff,
                                                        const u32* __restrict__ pedge,
                                                        const unsigned short* __restrict__ y,
                                                        const float* __restrict__ b,
                                                        float4* __restrict__ out4) {
    __shared__ float acc[BIN_ROWS * D];    // 16 KB
    const int tid = threadIdx.x;
    for (int i = tid; i < BIN_ROWS * D; i += 256) acc[i] = 0.f;
    __syncthreads();

    const int bin  = blockIdx.x;
    const int s    = binOff[bin];
    const int e    = binOff[bin + 1];
    const int lane = tid & 63;
    const int w    = tid >> 6;

    // each wave takes 64-edge chunks round-robin; lane loads one edge (coalesced),
    // then edges are broadcast via readlane and processed in batches of 8 gathers.
    for (int cbase = s + w * 64; cbase < e; cbase += 256) {
        const int idx = cbase + lane;
        u32 eu = (idx < e) ? pedge[idx] : 0u;   // pad edges decode to col=0,row=0,val=0
#pragma unroll
        for (int jj = 0; jj < 64; jj += 8) {
            u32 u[8]; unsigned short g[8];
#pragma unroll
            for (int j2 = 0; j2 < 8; ++j2) {
                u[j2] = __shfl(eu, jj + j2);                 // v_readlane (literal lane)
                g[j2] = y[(u[j2] >> 15) * D + lane];         // coalesced 128B row gather
            }
#pragma unroll
            for (int j2 = 0; j2 < 8; ++j2) {
                const float v = (float)(u[j2] & 511u) * (1.0f / 512.0f);
                const int   r = (int)((u[j2] >> 9) & 63u);
                atomicAdd(&acc[r * D + lane], v * bf16_to_f32(g[j2]));   // ds_add_f32
            }
        }
    }
    __syncthreads();

    // dense writeout + bias
    const int rowBase = bin * BIN_ROWS;
    for (int i = tid; i < BIN_ROWS * 16; i += 256) {
        const int rl = i >> 4, q = i & 15;
        const int row = rowBase + rl;
        if (row < N_NODES) {
            const float4 a  = ((const float4*)acc)[i];
            const float4 bv = ((const float4*)b)[q];
            out4[row * 16 + q] = make_float4(a.x + bv.x, a.y + bv.y, a.z + bv.z, a.w + bv.w);
        }
    }
}

// ---------------- fallback (small ws): atomic scatter ----------------
__global__ __launch_bounds__(256) void init_out_kernel(const float* __restrict__ b,
                                                       float* __restrict__ out) {
    const int i = blockIdx.x * blockDim.x + threadIdx.x;
    const int total4 = N_NODES * D / 4;
    if (i < total4) {
        const float4* b4 = reinterpret_cast<const float4*>(b);
        reinterpret_cast<float4*>(out)[i] = b4[i & 15];
    }
}

__global__ __launch_bounds__(256) void scatter_kernel(const int* __restrict__ erow,
                                                      const int* __restrict__ ecol,
                                                      const float* __restrict__ eval_,
                                                      const unsigned short* __restrict__ y,
                                                      float* __restrict__ out, int ne) {
    const int e    = blockIdx.x * 4 + (threadIdx.x >> 6);
    const int lane = threadIdx.x & 63;
    if (e >= ne) return;
    atomicAdd(&out[erow[e] * D + lane], eval_[e] * bf16_to_f32(y[ecol[e] * D + lane]));
}

extern "C" void kernel_launch(void* const* d_in, const int* in_sizes, int n_in,
                              void* d_out, int out_size, void* d_ws, size_t ws_size,
                              hipStream_t stream) {
    const float* x     = (const float*)d_in[0];
    const int*   erow  = (const int*)  d_in[1];
    const int*   ecol  = (const int*)  d_in[2];
    const float* eval_ = (const float*)d_in[3];
    const float* W     = (const float*)d_in[4];
    const float* b     = (const float*)d_in[5];
    float*       out   = (float*)d_out;
    const int ne = in_sizes[1];

    char* ws = (char*)d_ws;
    // workspace layout (256-aligned)
    const size_t Y_OFF     = 0;              // 100000*64*2 = 12,800,000 B
    const size_t PEDGE_OFF = 12800000;       // 1M * 4B = 4,000,000 B
    const size_t BCNT_OFF  = 16800000;       // 1563*4 -> 6,400
    const size_t BOFF_OFF  = 16806400;       // 1564*4 -> 6,400
    const size_t BCUR_OFF  = 16812800;       // 1563*4
    const size_t TOTAL     = 16819200;

    unsigned short* y = (unsigned short*)(ws + Y_OFF);

    if (ws_size >= TOTAL) {
        u32* pedge     = (u32*)(ws + PEDGE_OFF);
        int* binCounts = (int*)(ws + BCNT_OFF);
        int* binOff    = (int*)(ws + BOFF_OFF);
        int* binCursor = (int*)(ws + BCUR_OFF);

        // 1) y = bf16(x @ W^T); zeroes binCounts
        xw_kernel<<<3125, 256, 0, stream>>>(x, W, y, binCounts);

        // 2) coarse CSR (1563 bins of 64 rows)
        binhist_kernel<<<128, 256, 0, stream>>>(erow, binCounts, ne);
        binscan_kernel<<<1, 512, 0, stream>>>(binCounts, binOff, binCursor);
        partition_kernel<<<(ne + PE - 1) / PE, 256, 0, stream>>>(erow, ecol, eval_, binCursor, pedge, ne);

        // 3) per-bin LDS-accumulated aggregation + bias
        aggregate_kernel<<<NBINS, 256, 0, stream>>>(binOff, pedge, y, b, (float4*)out);
    } else {
        xw_kernel<<<3125, 256, 0, stream>>>(x, W, y, (int*)(ws + BCNT_OFF));
        init_out_kernel<<<(N_NODES * D / 4 + 255) / 256, 256, 0, stream>>>(b, out);
        scatter_kernel<<<(ne + 3) / 4, 256, 0, stream>>>(erow, ecol, eval_, y, out, ne);
    }
}

// Round 6
// 161.196 us; speedup vs baseline: 3.2773x; 3.2773x over previous
//
#include <hip/hip_runtime.h>

#define N_NODES 100000
#define D 64
#define BIN_ROWS 64
#define NBINS 1563          // ceil(100000 / 64)
#define PE 16384            // edges per partition block

typedef unsigned int u32;

__device__ __forceinline__ float bf16_to_f32(unsigned short u) {
    union { u32 i; float f; } c; c.i = ((u32)u) << 16; return c.f;
}
__device__ __forceinline__ unsigned short f32_to_bf16(float f) {
    union { float f; u32 i; } c; c.f = f;
    const u32 u = c.i;
    return (unsigned short)((u + 0x7FFFu + ((u >> 16) & 1u)) >> 16);
}

// ---------------- y = bf16(x @ W^T); block 0 zeroes binCounts ----------------
__global__ __launch_bounds__(256) void xw_kernel(const float* __restrict__ x,
                                                 const float* __restrict__ W,
                                                 unsigned short* __restrict__ y,
                                                 int* __restrict__ binCounts) {
    __shared__ float Ws[D][D + 1];
    __shared__ float xs[32][D];

    const int tid = threadIdx.x;
    if (blockIdx.x == 0) {
        for (int i = tid; i < NBINS; i += 256) binCounts[i] = 0;
    }
    for (int i = tid; i < D * D; i += 256) Ws[i >> 6][i & 63] = W[i];

    const int nodeBase = blockIdx.x * 32;
    for (int i = tid; i < 32 * D; i += 256) {
        const int n = nodeBase + (i >> 6);
        xs[i >> 6][i & 63] = (n < N_NODES) ? x[n * D + (i & 63)] : 0.f;
    }
    __syncthreads();

    const int wave = tid >> 6, j = tid & 63;
    for (int s = 0; s < 8; ++s) {
        const int local = wave * 8 + s;
        const int n = nodeBase + local;
        if (n >= N_NODES) break;
        float acc = 0.f;
#pragma unroll
        for (int k = 0; k < D; ++k) acc += xs[local][k] * Ws[j][k];
        y[n * D + j] = f32_to_bf16(acc);
    }
}

// ---------------- per-block LDS histogram of row>>6 (int LDS atomics: native) ----------------
__global__ __launch_bounds__(256) void binhist_kernel(const int* __restrict__ erow,
                                                      int* __restrict__ binCounts, int ne) {
    __shared__ int h[NBINS];
    for (int i = threadIdx.x; i < NBINS; i += 256) h[i] = 0;
    __syncthreads();
    const int stride = gridDim.x * 256;
    for (int e = blockIdx.x * 256 + threadIdx.x; e < ne; e += stride)
        atomicAdd(&h[erow[e] >> 6], 1);
    __syncthreads();
    for (int i = threadIdx.x; i < NBINS; i += 256)
        if (h[i]) atomicAdd(&binCounts[i], h[i]);
}

// ---------------- single-block exclusive scan of 1563 bin counts ----------------
__global__ __launch_bounds__(512) void binscan_kernel(const int* __restrict__ binCounts,
                                                      int* __restrict__ binOff,
                                                      int* __restrict__ binCursor) {
    __shared__ int sdat[512];
    const int tid = threadIdx.x;
    int v[4], sum = 0;
#pragma unroll
    for (int k = 0; k < 4; ++k) {
        const int i = tid * 4 + k;
        v[k] = (i < NBINS) ? binCounts[i] : 0;
        sum += v[k];
    }
    sdat[tid] = sum;
    __syncthreads();
    for (int d = 1; d < 512; d <<= 1) {
        const int t = (tid >= d) ? sdat[tid - d] : 0;
        __syncthreads();
        sdat[tid] += t;
        __syncthreads();
    }
    int run = sdat[tid] - sum;
#pragma unroll
    for (int k = 0; k < 4; ++k) {
        const int i = tid * 4 + k;
        if (i < NBINS) { binOff[i] = run; binCursor[i] = run; }
        run += v[k];
    }
    if (tid == 511) binOff[NBINS] = sdat[511];
}

// ---------------- partition: pack (col,localrow,q9val) into u32, bin-grouped ----------------
__global__ __launch_bounds__(256) void partition_kernel(const int* __restrict__ erow,
                                                        const int* __restrict__ ecol,
                                                        const float* __restrict__ eval_,
                                                        int* __restrict__ binCursor,
                                                        u32* __restrict__ pedge, int ne) {
    __shared__ int h[NBINS];
    __shared__ int lcur[NBINS];
    for (int i = threadIdx.x; i < NBINS; i += 256) h[i] = 0;
    __syncthreads();
    const int base = blockIdx.x * PE;
    const int end  = min(base + PE, ne);
    for (int e = base + threadIdx.x; e < end; e += 256)
        atomicAdd(&h[erow[e] >> 6], 1);
    __syncthreads();
    for (int i = threadIdx.x; i < NBINS; i += 256) {
        const int c = h[i];
        lcur[i] = c ? atomicAdd(&binCursor[i], c) : 0;
    }
    __syncthreads();
    for (int e = base + threadIdx.x; e < end; e += 256) {
        const int r = erow[e];
        const int bin = r >> 6;
        const int pos = atomicAdd(&lcur[bin], 1);
        int q = (int)(eval_[e] * 512.0f + 0.5f);
        q = (q > 511) ? 511 : q;
        pedge[pos] = ((u32)ecol[e] << 15) | ((u32)(r & 63) << 9) | (u32)q;
    }
}

// ---------------- aggregate: one block per 64-row bin, 16KB int LDS acc ----------------
// Edges fetched via wave-uniform scalar loads; contributions quantized to
// fixed-point 2^18 and accumulated with native ds_add_u32 (no float CAS loop).
__global__ __launch_bounds__(256) void aggregate_kernel(const int* __restrict__ binOff,
                                                        const u32* __restrict__ pedge,
                                                        const unsigned short* __restrict__ y,
                                                        const float* __restrict__ b,
                                                        float4* __restrict__ out4) {
    __shared__ int acc[BIN_ROWS * D];    // 16 KB
    const int tid = threadIdx.x;
    for (int i = tid; i < BIN_ROWS * D; i += 256) acc[i] = 0;
    __syncthreads();

    const int bin  = blockIdx.x;
    const int lane = tid & 63;
    const int w    = tid >> 6;
    const int s    = binOff[bin];
    const int e    = binOff[bin + 1];

    for (int bb0 = s + w * 16; bb0 < e; bb0 += 64) {
        const int bb = __builtin_amdgcn_readfirstlane(bb0);
        u32 u[16];
#pragma unroll
        for (int j = 0; j < 16; ++j) {          // wave-uniform -> s_load
            const int idx = bb + j;
            const u32 t = pedge[(idx < e) ? idx : (e - 1)];
            u[j] = (idx < e) ? t : 0u;          // pad decodes to vq=0 -> adds 0
        }
        unsigned short g[16];
#pragma unroll
        for (int j = 0; j < 16; ++j) {          // 16 concurrent 128B row gathers
            g[j] = y[(int)(u[j] >> 15) * D + lane];
        }
#pragma unroll
        for (int j = 0; j < 16; ++j) {
            const float vq = (float)(u[j] & 511u);          // val * 512
            const float yf = bf16_to_f32(g[j]);
            const int   qi = (int)(vq * yf * 512.0f);       // contribution * 2^18
            const int   r  = (int)((u[j] >> 9) & 63u);
            atomicAdd(&acc[r * D + lane], qi);              // ds_add_u32 (native)
        }
    }
    __syncthreads();

    // dense writeout + bias (dequant 2^-18)
    const int rowBase = bin * BIN_ROWS;
    const float INV = 1.0f / 262144.0f;
    for (int i = tid; i < BIN_ROWS * 16; i += 256) {
        const int rl = i >> 4, q = i & 15;
        const int row = rowBase + rl;
        if (row < N_NODES) {
            const int4  a  = ((const int4*)acc)[i];
            const float4 bv = ((const float4*)b)[q];
            out4[row * 16 + q] = make_float4((float)a.x * INV + bv.x,
                                             (float)a.y * INV + bv.y,
                                             (float)a.z * INV + bv.z,
                                             (float)a.w * INV + bv.w);
        }
    }
}

// ---------------- fallback (small ws): atomic scatter ----------------
__global__ __launch_bounds__(256) void init_out_kernel(const float* __restrict__ b,
                                                       float* __restrict__ out) {
    const int i = blockIdx.x * blockDim.x + threadIdx.x;
    const int total4 = N_NODES * D / 4;
    if (i < total4) {
        const float4* b4 = reinterpret_cast<const float4*>(b);
        reinterpret_cast<float4*>(out)[i] = b4[i & 15];
    }
}

__global__ __launch_bounds__(256) void scatter_kernel(const int* __restrict__ erow,
                                                      const int* __restrict__ ecol,
                                                      const float* __restrict__ eval_,
                                                      const unsigned short* __restrict__ y,
                                                      float* __restrict__ out, int ne) {
    const int e    = blockIdx.x * 4 + (threadIdx.x >> 6);
    const int lane = threadIdx.x & 63;
    if (e >= ne) return;
    atomicAdd(&out[erow[e] * D + lane], eval_[e] * bf16_to_f32(y[ecol[e] * D + lane]));
}

extern "C" void kernel_launch(void* const* d_in, const int* in_sizes, int n_in,
                              void* d_out, int out_size, void* d_ws, size_t ws_size,
                              hipStream_t stream) {
    const float* x     = (const float*)d_in[0];
    const int*   erow  = (const int*)  d_in[1];
    const int*   ecol  = (const int*)  d_in[2];
    const float* eval_ = (const float*)d_in[3];
    const float* W     = (const float*)d_in[4];
    const float* b     = (const float*)d_in[5];
    float*       out   = (float*)d_out;
    const int ne = in_sizes[1];

    char* ws = (char*)d_ws;
    // workspace layout (256-aligned)
    const size_t Y_OFF     = 0;              // 100000*64*2 = 12,800,000 B
    const size_t PEDGE_OFF = 12800000;       // 1M * 4B = 4,000,000 B
    const size_t BCNT_OFF  = 16800000;       // 1563*4
    const size_t BOFF_OFF  = 16806400;       // 1564*4
    const size_t BCUR_OFF  = 16812800;       // 1563*4
    const size_t TOTAL     = 16819200;

    unsigned short* y = (unsigned short*)(ws + Y_OFF);

    if (ws_size >= TOTAL) {
        u32* pedge     = (u32*)(ws + PEDGE_OFF);
        int* binCounts = (int*)(ws + BCNT_OFF);
        int* binOff    = (int*)(ws + BOFF_OFF);
        int* binCursor = (int*)(ws + BCUR_OFF);

        // 1) y = bf16(x @ W^T); zeroes binCounts
        xw_kernel<<<3125, 256, 0, stream>>>(x, W, y, binCounts);

        // 2) coarse CSR (1563 bins of 64 rows)
        binhist_kernel<<<128, 256, 0, stream>>>(erow, binCounts, ne);
        binscan_kernel<<<1, 512, 0, stream>>>(binCounts, binOff, binCursor);
        partition_kernel<<<(ne + PE - 1) / PE, 256, 0, stream>>>(erow, ecol, eval_, binCursor, pedge, ne);

        // 3) per-bin int-LDS-accumulated aggregation + bias
        aggregate_kernel<<<NBINS, 256, 0, stream>>>(binOff, pedge, y, b, (float4*)out);
    } else {
        xw_kernel<<<3125, 256, 0, stream>>>(x, W, y, (int*)(ws + BCNT_OFF));
        init_out_kernel<<<(N_NODES * D / 4 + 255) / 256, 256, 0, stream>>>(b, out);
        scatter_kernel<<<(ne + 3) / 4, 256, 0, stream>>>(erow, ecol, eval_, y, out, ne);
    }
}